// Round 1
// baseline (399.279 us; speedup 1.0000x reference)
//
#include <hip/hip_runtime.h>
#include <hip/hip_bf16.h>

// Triangle attention, S=384, D=128, H=4, HD=32.
// Pipeline: k0 weight-cast -> k1 LN+bias -> k2 qkv+g GEMM -> k3 attention -> k4 gate+out GEMM.
// All MFMA fragments use a consistent self-chosen k-mapping (k = 8*(lane>>4)+j for both A and B),
// which is correct independent of the HW's internal k permutation. C/D layout: col=lane&15,
// row=4*(lane>>4)+reg (HW-verified).

#define S_ 384
#define D_ 128
#define MTOT (S_*S_)

typedef __bf16 bf16;
typedef __bf16 bf16x8 __attribute__((ext_vector_type(8)));
typedef __bf16 bf16x2 __attribute__((ext_vector_type(2)));
typedef float  f32x4  __attribute__((ext_vector_type(4)));

// ---------------- workspace layout (bytes) ----------------
#define OFF_LN   0u            // bf16 [147456][128]  (reused as o_ws after k2)
#define OFF_Q    37748736u     // bf16 [S][H][S][32]
#define OFF_K    75497472u
#define OFF_V    113246208u
#define OFF_G    150994944u    // bf16 [147456][128]
#define OFF_BIAS 188743680u    // f32  [H][S][S]   (bias_t[h][j][i] = bias[h,i,j])
#define OFF_W2   191102976u    // bf16 [512][128]  (qkv_w rows 0..383, g_w rows 384..511)
#define OFF_OWB  191234048u    // bf16 [128][128]

// ---------------- k0: cast weights to bf16 ----------------
__global__ __launch_bounds__(256) void k0_convert(const float* __restrict__ qkv_w,
                                                  const float* __restrict__ g_w,
                                                  const float* __restrict__ o_w,
                                                  bf16* __restrict__ W2,
                                                  bf16* __restrict__ o_wb) {
    int idx = blockIdx.x * 256 + threadIdx.x;
    if (idx < 512 * 128) {
        float v = (idx < 384 * 128) ? qkv_w[idx] : g_w[idx - 384 * 128];
        W2[idx] = (bf16)v;
    }
    int idx2 = idx - 512 * 128;
    if (idx2 >= 0 && idx2 < 128 * 128) o_wb[idx2] = (bf16)o_w[idx2];
}

// ---------------- k1: LayerNorm (fp32) + triangle-bias projection ----------------
// one wave per position (i,j); lane handles channels 2l, 2l+1
__global__ __launch_bounds__(256) void k1_ln(const float* __restrict__ x,
                                             const float* __restrict__ ln_w,
                                             const float* __restrict__ ln_b,
                                             const float* __restrict__ bias_w,
                                             bf16* __restrict__ ln_ws,
                                             float* __restrict__ bias_t) {
    int wid = threadIdx.x >> 6, lane = threadIdx.x & 63;
    int pos = blockIdx.x * 4 + wid;              // [0, 147456)
    const float2 v = ((const float2*)(x + (size_t)pos * D_))[lane];
    float sum = v.x + v.y;
    float sumsq = v.x * v.x + v.y * v.y;
    #pragma unroll
    for (int off = 32; off; off >>= 1) {
        sum   += __shfl_xor(sum, off);
        sumsq += __shfl_xor(sumsq, off);
    }
    float mu   = sum * (1.0f / D_);
    float var  = sumsq * (1.0f / D_) - mu * mu;
    float rstd = rsqrtf(var + 1e-5f);
    float2 w  = ((const float2*)ln_w)[lane];
    float2 bb = ((const float2*)ln_b)[lane];
    float y0 = (v.x - mu) * rstd * w.x + bb.x;
    float y1 = (v.y - mu) * rstd * w.y + bb.y;
    bf16x2 yb; yb[0] = (bf16)y0; yb[1] = (bf16)y1;
    *(bf16x2*)(ln_ws + (size_t)pos * D_ + 2 * lane) = yb;

    int i = pos / S_, j = pos - i * S_;
    #pragma unroll
    for (int h = 0; h < 4; ++h) {
        float2 bw = ((const float2*)(bias_w + h * D_))[lane];
        float p = y0 * bw.x + y1 * bw.y;
        #pragma unroll
        for (int off = 32; off; off >>= 1) p += __shfl_xor(p, off);
        if (lane == 0) bias_t[((size_t)h * S_ + j) * S_ + i] = p;   // transposed store
    }
}

// ---------------- k2: [147456,128] @ W2^T -> qkv (scattered heads) + g ----------------
// BM=64, BN=128, full K=128 staged in padded LDS. 4 waves, each 32x64.
__global__ __launch_bounds__(256) void k2_proj(const bf16* __restrict__ ln_ws,
                                               const bf16* __restrict__ W2,
                                               bf16* __restrict__ q_ws,
                                               bf16* __restrict__ k_ws,
                                               bf16* __restrict__ v_ws,
                                               bf16* __restrict__ g_ws) {
    __shared__ __align__(16) char smem[64 * 272 + 128 * 272];
    char* As = smem;                 // [64][272B]  (128 bf16 + 8 pad)
    char* Bs = smem + 64 * 272;      // [128][272B]
    int t = threadIdx.x;
    int m0 = blockIdx.x * 64;
    int n0 = blockIdx.y * 128;
    #pragma unroll
    for (int it = 0; it < 4; ++it) {
        int byte = it * 4096 + t * 16;
        int row = byte >> 8, colb = byte & 255;
        int4 val = *(const int4*)((const char*)ln_ws + (size_t)(m0 + row) * 256 + colb);
        *(int4*)(As + row * 272 + colb) = val;
    }
    #pragma unroll
    for (int it = 0; it < 8; ++it) {
        int byte = it * 4096 + t * 16;
        int row = byte >> 8, colb = byte & 255;
        int4 val = *(const int4*)((const char*)W2 + (size_t)(n0 + row) * 256 + colb);
        *(int4*)(Bs + row * 272 + colb) = val;
    }
    __syncthreads();
    int wid = t >> 6, lane = t & 63, lr = lane & 15, g = lane >> 4;
    int wm = wid >> 1, wn = wid & 1;           // wave tile 32x64
    f32x4 acc[2][4] = {};
    #pragma unroll
    for (int ks = 0; ks < 4; ++ks) {
        bf16x8 af[2], bfr[4];
        #pragma unroll
        for (int mt = 0; mt < 2; ++mt)
            af[mt] = *(const bf16x8*)(As + (wm * 32 + mt * 16 + lr) * 272 + ks * 64 + g * 16);
        #pragma unroll
        for (int nt = 0; nt < 4; ++nt)
            bfr[nt] = *(const bf16x8*)(Bs + (wn * 64 + nt * 16 + lr) * 272 + ks * 64 + g * 16);
        #pragma unroll
        for (int mt = 0; mt < 2; ++mt)
            #pragma unroll
            for (int nt = 0; nt < 4; ++nt)
                acc[mt][nt] = __builtin_amdgcn_mfma_f32_16x16x32_bf16(af[mt], bfr[nt], acc[mt][nt], 0, 0, 0);
    }
    #pragma unroll
    for (int mt = 0; mt < 2; ++mt)
        #pragma unroll
        for (int nt = 0; nt < 4; ++nt)
            #pragma unroll
            for (int i = 0; i < 4; ++i) {
                int m = m0 + wm * 32 + mt * 16 + g * 4 + i;
                int n = n0 + wn * 64 + nt * 16 + lr;
                bf16 val = (bf16)acc[mt][nt][i];
                if (n < 384) {
                    int comp = n >> 7, h = (n >> 5) & 3, d = n & 31;
                    int b = m / 384, jj = m - b * 384;
                    bf16* dst = (comp == 0) ? q_ws : (comp == 1) ? k_ws : v_ws;
                    dst[(((size_t)b * 4 + h) * 384 + jj) * 32 + d] = val;
                } else {
                    g_ws[(size_t)m * 128 + (n - 384)] = val;
                }
            }
}

// ---------------- k3: attention, one block per (b,h) ----------------
__global__ __launch_bounds__(256) void k3_attn(const bf16* __restrict__ q_ws,
                                               const bf16* __restrict__ k_ws,
                                               const bf16* __restrict__ v_ws,
                                               const float* __restrict__ bias_t,
                                               const float* __restrict__ mask,
                                               bf16* __restrict__ o_ws) {
    __shared__ __align__(16) char smem[30720 + 25088 + 5120];
    char* Ksh = smem;                    // [384][80B]  (32 bf16 + 8 pad)
    char* Vt  = smem + 30720;            // [32][784B]  (V transposed: [d][kpos], 384 bf16 + 8 pad)
    char* Pl  = smem + 30720 + 25088;    // per-wave [16][80B] P chunk
    int t = threadIdx.x;
    int bh = blockIdx.x;
    int b = bh >> 2, h = bh & 3;
    const char* kbase = (const char*)(k_ws + (size_t)bh * 384 * 32);
    const char* vbase = (const char*)(v_ws + (size_t)bh * 384 * 32);
    #pragma unroll
    for (int it = 0; it < 6; ++it) {
        int byte = it * 4096 + t * 16;
        int row = byte >> 6, colb = byte & 63;
        int4 val = *(const int4*)(kbase + byte);
        *(int4*)(Ksh + row * 80 + colb) = val;
    }
    #pragma unroll
    for (int it = 0; it < 6; ++it) {
        int byte = it * 4096 + t * 16;
        int row = byte >> 6, colb = byte & 63;
        bf16x8 v8 = *(const bf16x8*)(vbase + byte);
        int d0 = colb >> 1;
        #pragma unroll
        for (int jj = 0; jj < 8; ++jj)
            *(bf16*)(Vt + (d0 + jj) * 784 + row * 2) = v8[jj];
    }
    __syncthreads();
    int wid = t >> 6, lane = t & 63, lr = lane & 15, g = lane >> 4;
    char* Pw = Pl + wid * 16 * 80;
    const float scale = 0.17677669529663687f;   // 1/sqrt(32)
    for (int ch = 0; ch < 6; ++ch) {
        int q0 = ch * 64 + wid * 16;
        bf16x8 qf = *(const bf16x8*)((const char*)q_ws + ((size_t)bh * 384 + q0 + lr) * 64 + g * 16);
        f32x4 s[24];
        #pragma unroll
        for (int nt = 0; nt < 24; ++nt) s[nt] = (f32x4){0.f, 0.f, 0.f, 0.f};
        #pragma unroll
        for (int nt = 0; nt < 24; ++nt) {
            bf16x8 kf = *(const bf16x8*)(Ksh + (nt * 16 + lr) * 80 + g * 16);
            s[nt] = __builtin_amdgcn_mfma_f32_16x16x32_bf16(qf, kf, s[nt], 0, 0, 0);
        }
        // scale + bias + mask, track row max
        float mx[4] = {-1e30f, -1e30f, -1e30f, -1e30f};
        #pragma unroll
        for (int nt = 0; nt < 24; ++nt) {
            f32x4 bias4 = *(const f32x4*)(bias_t + ((size_t)h * 384 + nt * 16 + lr) * 384 + q0 + g * 4);
            float mk = mask[nt * 16 + lr];
            #pragma unroll
            for (int i = 0; i < 4; ++i) {
                float sv = s[nt][i] * scale + bias4[i] + mk;
                s[nt][i] = sv;
                mx[i] = fmaxf(mx[i], sv);
            }
        }
        #pragma unroll
        for (int i = 0; i < 4; ++i)
            #pragma unroll
            for (int off = 8; off; off >>= 1) mx[i] = fmaxf(mx[i], __shfl_xor(mx[i], off));
        float sm[4] = {0.f, 0.f, 0.f, 0.f};
        #pragma unroll
        for (int nt = 0; nt < 24; ++nt)
            #pragma unroll
            for (int i = 0; i < 4; ++i) {
                float p = __expf(s[nt][i] - mx[i]);
                s[nt][i] = p;
                sm[i] += p;
            }
        #pragma unroll
        for (int i = 0; i < 4; ++i) {
            #pragma unroll
            for (int off = 8; off; off >>= 1) sm[i] += __shfl_xor(sm[i], off);
            sm[i] = 1.0f / sm[i];
        }
        // PV: route P through per-wave LDS chunk (transpose C-layout -> A-layout)
        f32x4 oacc[2] = {};
        #pragma unroll
        for (int kt = 0; kt < 12; ++kt) {
            #pragma unroll
            for (int u = 0; u < 2; ++u) {
                int nt = kt * 2 + u;
                #pragma unroll
                for (int i = 0; i < 4; ++i)
                    *(bf16*)(Pw + (g * 4 + i) * 80 + (u * 16 + lr) * 2) = (bf16)s[nt][i];
            }
            bf16x8 pf = *(const bf16x8*)(Pw + lr * 80 + g * 16);
            #pragma unroll
            for (int dt = 0; dt < 2; ++dt) {
                bf16x8 vf = *(const bf16x8*)(Vt + (dt * 16 + lr) * 784 + kt * 64 + g * 16);
                oacc[dt] = __builtin_amdgcn_mfma_f32_16x16x32_bf16(pf, vf, oacc[dt], 0, 0, 0);
            }
        }
        #pragma unroll
        for (int dt = 0; dt < 2; ++dt)
            #pragma unroll
            for (int i = 0; i < 4; ++i) {
                float val = oacc[dt][i] * sm[i];
                o_ws[((size_t)b * 384 + q0 + g * 4 + i) * 128 + h * 32 + dt * 16 + lr] = (bf16)val;
            }
    }
}

// ---------------- k4: out = (o * sigmoid(g)) @ o_w^T ----------------
__global__ __launch_bounds__(256) void k4_out(const bf16* __restrict__ o_ws,
                                              const bf16* __restrict__ g_ws,
                                              const bf16* __restrict__ o_wb,
                                              float* __restrict__ out) {
    __shared__ __align__(16) char smem[64 * 272 + 128 * 272];
    char* As = smem;
    char* Bs = smem + 64 * 272;
    int t = threadIdx.x;
    int m0 = blockIdx.x * 64;
    #pragma unroll
    for (int it = 0; it < 4; ++it) {
        int byte = it * 4096 + t * 16;
        int row = byte >> 8, colb = byte & 255;
        bf16x8 o8 = *(const bf16x8*)((const char*)o_ws + (size_t)(m0 + row) * 256 + colb);
        bf16x8 g8 = *(const bf16x8*)((const char*)g_ws + (size_t)(m0 + row) * 256 + colb);
        bf16x8 a8;
        #pragma unroll
        for (int j = 0; j < 8; ++j) {
            float ov = (float)o8[j], gv = (float)g8[j];
            a8[j] = (bf16)(ov / (1.0f + __expf(-gv)));
        }
        *(bf16x8*)(As + row * 272 + colb) = a8;
    }
    #pragma unroll
    for (int it = 0; it < 8; ++it) {
        int byte = it * 4096 + t * 16;
        int row = byte >> 8, colb = byte & 255;
        *(int4*)(Bs + row * 272 + colb) = *(const int4*)((const char*)o_wb + (size_t)row * 256 + colb);
    }
    __syncthreads();
    int wid = t >> 6, lane = t & 63, lr = lane & 15, g = lane >> 4;
    int wm = wid >> 1, wn = wid & 1;
    f32x4 acc[2][4] = {};
    #pragma unroll
    for (int ks = 0; ks < 4; ++ks) {
        bf16x8 af[2], bfr[4];
        #pragma unroll
        for (int mt = 0; mt < 2; ++mt)
            af[mt] = *(const bf16x8*)(As + (wm * 32 + mt * 16 + lr) * 272 + ks * 64 + g * 16);
        #pragma unroll
        for (int nt = 0; nt < 4; ++nt)
            bfr[nt] = *(const bf16x8*)(Bs + (wn * 64 + nt * 16 + lr) * 272 + ks * 64 + g * 16);
        #pragma unroll
        for (int mt = 0; mt < 2; ++mt)
            #pragma unroll
            for (int nt = 0; nt < 4; ++nt)
                acc[mt][nt] = __builtin_amdgcn_mfma_f32_16x16x32_bf16(af[mt], bfr[nt], acc[mt][nt], 0, 0, 0);
    }
    #pragma unroll
    for (int mt = 0; mt < 2; ++mt)
        #pragma unroll
        for (int nt = 0; nt < 4; ++nt)
            #pragma unroll
            for (int i = 0; i < 4; ++i) {
                int m = m0 + wm * 32 + mt * 16 + g * 4 + i;
                int n = wn * 64 + nt * 16 + lr;
                out[(size_t)m * 128 + n] = acc[mt][nt][i];
            }
}

extern "C" void kernel_launch(void* const* d_in, const int* in_sizes, int n_in,
                              void* d_out, int out_size, void* d_ws, size_t ws_size,
                              hipStream_t stream) {
    const float* x      = (const float*)d_in[0];
    const float* mask   = (const float*)d_in[1];
    const float* ln_w   = (const float*)d_in[2];
    const float* ln_b   = (const float*)d_in[3];
    const float* bias_w = (const float*)d_in[4];
    const float* qkv_w  = (const float*)d_in[5];
    const float* g_w    = (const float*)d_in[6];
    const float* o_w    = (const float*)d_in[7];
    char* ws = (char*)d_ws;
    bf16*  ln_ws  = (bf16*)(ws + OFF_LN);
    bf16*  q_ws   = (bf16*)(ws + OFF_Q);
    bf16*  k_ws   = (bf16*)(ws + OFF_K);
    bf16*  v_ws   = (bf16*)(ws + OFF_V);
    bf16*  g_ws   = (bf16*)(ws + OFF_G);
    float* bias_t = (float*)(ws + OFF_BIAS);
    bf16*  W2     = (bf16*)(ws + OFF_W2);
    bf16*  o_wb   = (bf16*)(ws + OFF_OWB);
    bf16*  o_ws   = ln_ws;   // alias: ln dead after k2
    float* out    = (float*)d_out;

    k0_convert<<<dim3(320), dim3(256), 0, stream>>>(qkv_w, g_w, o_w, W2, o_wb);
    k1_ln<<<dim3(MTOT / 4), dim3(256), 0, stream>>>(x, ln_w, ln_b, bias_w, ln_ws, bias_t);
    k2_proj<<<dim3(MTOT / 64, 4), dim3(256), 0, stream>>>(ln_ws, W2, q_ws, k_ws, v_ws, g_ws);
    k3_attn<<<dim3(S_ * 4), dim3(256), 0, stream>>>(q_ws, k_ws, v_ws, bias_t, mask, o_ws);
    k4_out<<<dim3(MTOT / 64), dim3(256), 0, stream>>>(o_ws, g_ws, o_wb, out);
}